// Round 1
// baseline (4873.709 us; speedup 1.0000x reference)
//
#include <hip/hip_runtime.h>
#include <hip/hip_bf16.h>
#include <cstdint>
#include <cstddef>

// B=64 T=512 E=768 H=256 L=9.  BiLSTM + linear + CRF loglik (scalar out).
// Round 1: correctness-first baseline. Recurrence = 8 chains (2 dirs x 4
// batch-groups of 16), one 1024-thread WG each, W_hh streamed from L2 every
// step (known bottleneck, ~1-2us/step); optimize in later rounds.

typedef __attribute__((ext_vector_type(8))) short short8;
typedef __attribute__((ext_vector_type(4))) float floatx4;
typedef unsigned short ushort_t;
typedef unsigned int uint_t;

#define NB   64
#define NT   512
#define NE   768
#define NH   256
#define NL   9
#define NG   1024   // 4*H
#define NCC  2048   // both dirs' gates

__device__ inline float b2f(ushort_t u) {
    union { uint_t i; float f; } v; v.i = ((uint_t)u) << 16; return v.f;
}
__device__ inline ushort_t f2b(float f) {
    union { float f; uint_t i; } v; v.f = f;
    uint_t r = (v.i + 0x7FFFu + ((v.i >> 16) & 1u)) >> 16;
    return (ushort_t)r;
}
__device__ inline float sigf(float x) { return 1.0f / (1.0f + __expf(-x)); }
__device__ inline float tanhfast(float x) { return 1.0f - 2.0f / (1.0f + __expf(2.0f * x)); }

// ---------------- K1: embeddings (B,T,E) f32 -> xbf (T,B,E) bf16 ------------
__global__ void conv_x(const float* __restrict__ emb, ushort_t* __restrict__ xbf) {
    int id = blockIdx.x * blockDim.x + threadIdx.x;      // over T*B*(E/4)
    int t  = id / (NB * (NE / 4));
    int rm = id - t * (NB * (NE / 4));
    int b  = rm / (NE / 4);
    int e4 = rm - b * (NE / 4);
    const float4 v = *(const float4*)(emb + ((size_t)b * NT + t) * NE + e4 * 4);
    ushort_t o[4] = { f2b(v.x), f2b(v.y), f2b(v.z), f2b(v.w) };
    *(uint2*)(xbf + ((size_t)t * NB + b) * NE + e4 * 4) = *(const uint2*)o;
}

// ---------------- K1b: weights -> bf16 (Wcat, Whh), bias concat -------------
__global__ void conv_w(const float* __restrict__ Wihf, const float* __restrict__ Wihb,
                       const float* __restrict__ Whhf, const float* __restrict__ Whhb,
                       const float* __restrict__ bf,   const float* __restrict__ bb,
                       ushort_t* __restrict__ wcat, ushort_t* __restrict__ whh,
                       float* __restrict__ bias) {
    int idx = blockIdx.x * blockDim.x + threadIdx.x;
    const int NW1 = NCC * NE;            // 1572864
    const int NW2 = 2 * NG * NH;         // 524288
    if (idx < NW1) {
        int row = idx / NE, col = idx - row * NE;
        float s = (row < NG) ? Wihf[(size_t)row * NE + col]
                             : Wihb[(size_t)(row - NG) * NE + col];
        wcat[idx] = f2b(s);
    } else if (idx < NW1 + NW2) {
        int j = idx - NW1;
        float s = (j < NG * NH) ? Whhf[j] : Whhb[j - NG * NH];
        whh[j] = f2b(s);
    } else if (idx < NW1 + NW2 + NCC) {
        int j = idx - NW1 - NW2;
        bias[j] = (j < NG) ? bf[j] : bb[j - NG];
    }
}

// ---------------- K2: xg = xbf(32768x768) @ wcat^T(2048x768) + bias ---------
// 128x128 tile, BK=64, 256 threads (4 waves, 2x2 of 64x64), bf16 out.
__global__ __launch_bounds__(256) void gemm_xg(const ushort_t* __restrict__ A,
                                               const ushort_t* __restrict__ W,
                                               const float* __restrict__ bias,
                                               ushort_t* __restrict__ C) {
    __shared__ ushort_t As[128 * 72];
    __shared__ ushort_t Bs[128 * 72];
    const int tid = threadIdx.x;
    const int wave = tid >> 6, lane = tid & 63;
    const int q = lane >> 4, m16 = lane & 15;
    const int wm = wave & 1, wn = wave >> 1;
    const int m0 = blockIdx.y * 128, n0 = blockIdx.x * 128;

    floatx4 acc[4][4];
    #pragma unroll
    for (int i = 0; i < 4; ++i)
        #pragma unroll
        for (int j = 0; j < 4; ++j) acc[i][j] = (floatx4){0.f, 0.f, 0.f, 0.f};

    for (int kt = 0; kt < NE / 64; ++kt) {
        __syncthreads();
        #pragma unroll
        for (int it = 0; it < 4; ++it) {
            int chunk = tid + it * 256;         // 0..1023
            int row = chunk >> 3, kc = chunk & 7;
            *(uint4*)(&As[row * 72 + kc * 8]) =
                *(const uint4*)(A + (size_t)(m0 + row) * NE + kt * 64 + kc * 8);
            *(uint4*)(&Bs[row * 72 + kc * 8]) =
                *(const uint4*)(W + (size_t)(n0 + row) * NE + kt * 64 + kc * 8);
        }
        __syncthreads();
        #pragma unroll
        for (int ks = 0; ks < 2; ++ks) {
            short8 af[4], bfr[4];
            #pragma unroll
            for (int mt = 0; mt < 4; ++mt)
                af[mt] = *(const short8*)(&As[(wm * 64 + mt * 16 + m16) * 72 + ks * 32 + q * 8]);
            #pragma unroll
            for (int nt = 0; nt < 4; ++nt)
                bfr[nt] = *(const short8*)(&Bs[(wn * 64 + nt * 16 + m16) * 72 + ks * 32 + q * 8]);
            #pragma unroll
            for (int mt = 0; mt < 4; ++mt)
                #pragma unroll
                for (int nt = 0; nt < 4; ++nt)
                    acc[mt][nt] = __builtin_amdgcn_mfma_f32_16x16x32_bf16(
                        af[mt], bfr[nt], acc[mt][nt], 0, 0, 0);
        }
    }
    float bcol[4];
    #pragma unroll
    for (int nt = 0; nt < 4; ++nt) bcol[nt] = bias[n0 + wn * 64 + nt * 16 + m16];
    #pragma unroll
    for (int mt = 0; mt < 4; ++mt)
        #pragma unroll
        for (int nt = 0; nt < 4; ++nt) {
            int gn = n0 + wn * 64 + nt * 16 + m16;
            #pragma unroll
            for (int r = 0; r < 4; ++r) {
                int gm = m0 + wm * 64 + mt * 16 + q * 4 + r;
                C[(size_t)gm * NCC + gn] = f2b(acc[mt][nt][r] + bcol[nt]);
            }
        }
}

// ---------------- K3: recurrence. 8 blocks = (dir, batch-group of 16) -------
__global__ __launch_bounds__(1024, 1) void lstm_k(const ushort_t* __restrict__ xg,
                                                  const ushort_t* __restrict__ whh,
                                                  ushort_t* __restrict__ hhist) {
    const int d = blockIdx.x >> 2;            // 0 fwd, 1 bwd
    const int b0 = (blockIdx.x & 3) * 16;
    const int tid = threadIdx.x;
    const int w = tid >> 6, lane = tid & 63;
    const int q = lane >> 4, m16 = lane & 15;
    const int hu = w * 16 + m16;              // hidden unit this lane owns

    __shared__ ushort_t hbuf[2][16 * 264];
    for (int i = tid; i < 16 * 264; i += 1024) hbuf[0][i] = 0;
    float c[4] = {0.f, 0.f, 0.f, 0.f};
    const ushort_t* wp = whh + (size_t)d * NG * NH;
    __syncthreads();

    for (int s = 0; s < NT; ++s) {
        const int t = d ? (NT - 1 - s) : s;
        const int rd = s & 1, wr = rd ^ 1;

        // xg for this step (independent of h -> issue early)
        float xv[4][4];
        #pragma unroll
        for (int nt = 0; nt < 4; ++nt) {
            int col = d * NG + nt * NH + hu;
            #pragma unroll
            for (int r = 0; r < 4; ++r) {
                size_t row = (size_t)t * NB + b0 + q * 4 + r;
                xv[nt][r] = b2f(xg[row * NCC + col]);
            }
        }
        // A fragments: h_prev[16 x 256]
        short8 af[8];
        #pragma unroll
        for (int ks = 0; ks < 8; ++ks)
            af[ks] = *(const short8*)(&hbuf[rd][m16 * 264 + ks * 32 + q * 8]);

        float gv[4][4];
        #pragma unroll
        for (int nt = 0; nt < 4; ++nt) {
            floatx4 acc = (floatx4){0.f, 0.f, 0.f, 0.f};
            const ushort_t* wb = wp + (size_t)(nt * NH + hu) * NH;
            #pragma unroll
            for (int ks = 0; ks < 8; ++ks) {
                short8 bfr = *(const short8*)(wb + ks * 32 + q * 8);
                acc = __builtin_amdgcn_mfma_f32_16x16x32_bf16(af[ks], bfr, acc, 0, 0, 0);
            }
            #pragma unroll
            for (int r = 0; r < 4; ++r) gv[nt][r] = acc[r] + xv[nt][r];
        }
        #pragma unroll
        for (int r = 0; r < 4; ++r) {
            float ig = sigf(gv[0][r]);
            float fg = sigf(gv[1][r]);
            float gg = tanhfast(gv[2][r]);
            float og = sigf(gv[3][r]);
            c[r] = fg * c[r] + ig * gg;
            float h = og * tanhfast(c[r]);
            ushort_t hb = f2b(h);
            int brow = q * 4 + r;
            hbuf[wr][brow * 264 + hu] = hb;
            hhist[(((size_t)d * NT + t) * NB + (b0 + brow)) * NH + hu] = hb;
        }
        __syncthreads();
    }
}

// ---------------- K4: em[t,b,l] = feats . W_lin[l] + b_lin ------------------
__global__ void em_k(const ushort_t* __restrict__ hhist, const float* __restrict__ Wlin,
                     const float* __restrict__ blin, float* __restrict__ em) {
    const int t = blockIdx.x;
    const int tid = threadIdx.x;          // 576 threads
    __shared__ float Ws[NL * 520];
    for (int idx = tid; idx < NL * 2 * NH; idx += 576) {
        int l = idx >> 9, k = idx & 511;
        Ws[l * 520 + k] = Wlin[l * 2 * NH + k];
    }
    __syncthreads();
    const int b = tid / NL, l = tid - b * NL;
    const ushort_t* hf = hhist + ((size_t)t * NB + b) * NH;
    const ushort_t* hb = hf + (size_t)NT * NB * NH;
    float acc = blin[l];
    #pragma unroll 4
    for (int kc = 0; kc < NH / 8; ++kc) {
        uint4 u = *(const uint4*)(hf + kc * 8);
        const uint_t* uu = (const uint_t*)&u;
        #pragma unroll
        for (int j = 0; j < 4; ++j) {
            acc += b2f((ushort_t)(uu[j] & 0xFFFF)) * Ws[l * 520 + kc * 8 + 2 * j];
            acc += b2f((ushort_t)(uu[j] >> 16))    * Ws[l * 520 + kc * 8 + 2 * j + 1];
        }
    }
    #pragma unroll 4
    for (int kc = 0; kc < NH / 8; ++kc) {
        uint4 u = *(const uint4*)(hb + kc * 8);
        const uint_t* uu = (const uint_t*)&u;
        #pragma unroll
        for (int j = 0; j < 4; ++j) {
            acc += b2f((ushort_t)(uu[j] & 0xFFFF)) * Ws[l * 520 + NH + kc * 8 + 2 * j];
            acc += b2f((ushort_t)(uu[j] >> 16))    * Ws[l * 520 + NH + kc * 8 + 2 * j + 1];
        }
    }
    em[((size_t)t * NB + b) * NL + l] = acc;
}

// ---------------- K5: CRF numerator per batch -------------------------------
__global__ void num_k(const float* __restrict__ em, const int* __restrict__ mask,
                      const int* __restrict__ labels, const float* __restrict__ start,
                      const float* __restrict__ endt, const float* __restrict__ trans,
                      float* __restrict__ numbuf) {
    const int b = threadIdx.x;     // 64 threads, 1 block
    int len = 0;
    #pragma unroll 8
    for (int t = 0; t < NT; ++t) len += (mask[b * NT + t] != 0);
    int tag0 = labels[b * NT];
    float num = start[tag0] + em[(size_t)b * NL + tag0];
    #pragma unroll 4
    for (int t = 1; t < NT; ++t) {
        if (t < len) {
            int tp = labels[b * NT + t - 1];
            int tg = labels[b * NT + t];
            num += trans[tp * NL + tg] + em[((size_t)t * NB + b) * NL + tg];
        }
    }
    num += endt[labels[b * NT + len - 1]];
    numbuf[b] = num;
}

// ---------------- K6: CRF forward (logZ), diff = logZ - num -----------------
__global__ void crf_k(const float* __restrict__ em, const int* __restrict__ mask,
                      const float* __restrict__ start, const float* __restrict__ endt,
                      const float* __restrict__ trans, const float* __restrict__ numbuf,
                      float* __restrict__ diff) {
    const int b = blockIdx.x;
    const int lane = threadIdx.x;       // 64 threads = 1 wave
    // length (prefix mask)
    int cnt = 0;
    for (int t = lane; t < NT; t += 64) cnt += (mask[b * NT + t] != 0);
    #pragma unroll
    for (int off = 32; off > 0; off >>= 1) cnt += __shfl_down(cnt, off);
    const int len = __shfl(cnt, 0);

    float tcol[NL];
    #pragma unroll
    for (int i = 0; i < NL; ++i) tcol[i] = (lane < NL) ? trans[i * NL + lane] : 0.f;
    float endv = (lane < NL) ? endt[lane] : 0.f;
    float score = (lane < NL) ? start[lane] + em[(size_t)b * NL + lane] : -1e30f;

    for (int t = 1; t < len; ++t) {
        float emv = (lane < NL) ? em[((size_t)t * NB + b) * NL + lane] : 0.f;
        float sv[NL];
        #pragma unroll
        for (int i = 0; i < NL; ++i) sv[i] = __shfl(score, i) + tcol[i];
        float m = sv[0];
        #pragma unroll
        for (int i = 1; i < NL; ++i) m = fmaxf(m, sv[i]);
        float sum = 0.f;
        #pragma unroll
        for (int i = 0; i < NL; ++i) sum += __expf(sv[i] - m);
        float nxt = m + __logf(sum) + emv;
        if (lane < NL) score = nxt;
    }
    float v = (lane < NL) ? score + endv : -1e30f;
    float m = -1e30f;
    float sv[NL];
    #pragma unroll
    for (int i = 0; i < NL; ++i) { sv[i] = __shfl(v, i); m = fmaxf(m, sv[i]); }
    float sum = 0.f;
    #pragma unroll
    for (int i = 0; i < NL; ++i) sum += __expf(sv[i] - m);
    float logZ = m + __logf(sum);
    if (lane == 0) diff[b] = logZ - numbuf[b];
}

// ---------------- K7: mean over batch -> d_out ------------------------------
__global__ void final_k(const float* __restrict__ diff, float* __restrict__ out) {
    float v = diff[threadIdx.x];
    #pragma unroll
    for (int off = 32; off > 0; off >>= 1) v += __shfl_down(v, off);
    if (threadIdx.x == 0) out[0] = v * (1.0f / NB);
}

extern "C" void kernel_launch(void* const* d_in, const int* in_sizes, int n_in,
                              void* d_out, int out_size, void* d_ws, size_t ws_size,
                              hipStream_t stream) {
    const float* emb   = (const float*)d_in[0];
    const float* Wihf  = (const float*)d_in[1];
    const float* Whhf  = (const float*)d_in[2];
    const float* bf    = (const float*)d_in[3];
    const float* Wihb  = (const float*)d_in[4];
    const float* Whhb  = (const float*)d_in[5];
    const float* bb    = (const float*)d_in[6];
    const float* Wlin  = (const float*)d_in[7];
    const float* blin  = (const float*)d_in[8];
    const float* start = (const float*)d_in[9];
    const float* endt  = (const float*)d_in[10];
    const float* trans = (const float*)d_in[11];
    const int*   mask  = (const int*)d_in[12];
    const int*   labels= (const int*)d_in[13];

    char* ws = (char*)d_ws;
    ushort_t* xbf   = (ushort_t*)(ws + 0);                     // 50,331,648
    ushort_t* wcat  = (ushort_t*)(ws + 50331648);              //  3,145,728
    ushort_t* whhbf = (ushort_t*)(ws + 53477376);              //  1,048,576
    float*    bias  = (float*)   (ws + 54525952);              //      8,192
    ushort_t* xg    = (ushort_t*)(ws + 54534144);              // 134,217,728
    ushort_t* hhist = (ushort_t*)(ws + 188751872);             //  33,554,432
    float*    em    = (float*)   (ws + 222306304);             //   1,179,648
    float*    numb  = (float*)   (ws + 223485952);             //        256
    float*    diff  = (float*)   (ws + 223486208);             //        256

    conv_x<<<NT * NB * (NE / 4) / 256, 256, 0, stream>>>(emb, xbf);
    conv_w<<<(NCC * NE + 2 * NG * NH + NCC) / 256, 256, 0, stream>>>(
        Wihf, Wihb, Whhf, Whhb, bf, bb, wcat, whhbf, bias);
    gemm_xg<<<dim3(NCC / 128, NT * NB / 128), 256, 0, stream>>>(xbf, wcat, bias, xg);
    lstm_k<<<8, 1024, 0, stream>>>(xg, whhbf, hhist);
    em_k<<<NT, 576, 0, stream>>>(hhist, Wlin, blin, em);
    num_k<<<1, 64, 0, stream>>>(em, mask, labels, start, endt, trans, numb);
    crf_k<<<NB, 64, 0, stream>>>(em, mask, start, endt, trans, numb, diff);
    final_k<<<1, 64, 0, stream>>>(diff, (float*)d_out);
}

// Round 2
// 3711.652 us; speedup vs baseline: 1.3131x; 1.3131x over previous
//
#include <hip/hip_runtime.h>
#include <hip/hip_bf16.h>
#include <cstdint>
#include <cstddef>

// B=64 T=512 E=768 H=256 L=9.  BiLSTM + linear + CRF loglik (scalar out).
// R2: LSTM recurrence distributed across 16 WGs (2 dirs x 8 gate-slices).
// W_hh slice (64KB) LDS-resident; per-step h exchange via global memory with
// agent-scope flag sync (producer: release+atomicAdd, consumer: relaxed poll
// + acquire fence). h buffers are per-step disjoint -> no WAR hazards.

typedef __attribute__((ext_vector_type(8))) short short8;
typedef __attribute__((ext_vector_type(4))) float floatx4;
typedef unsigned short ushort_t;
typedef unsigned int uint_t;

#define NB   64
#define NT   512
#define NE   768
#define NH   256
#define NL   9
#define NG   1024   // 4*H
#define NCC  2048   // both dirs' gates
#define GPD  8      // workgroups per direction
#define HSL  32     // hidden units per WG (NH/GPD)
#define HSLOT 16384 // 64*256 elems per h time-slot

__device__ inline float b2f(ushort_t u) {
    union { uint_t i; float f; } v; v.i = ((uint_t)u) << 16; return v.f;
}
__device__ inline ushort_t f2b(float f) {
    union { float f; uint_t i; } v; v.f = f;
    uint_t r = (v.i + 0x7FFFu + ((v.i >> 16) & 1u)) >> 16;
    return (ushort_t)r;
}
__device__ inline float sigf(float x) { return 1.0f / (1.0f + __expf(-x)); }
__device__ inline float tanhfast(float x) { return 1.0f - 2.0f / (1.0f + __expf(2.0f * x)); }

// ---------------- K0: zero sync counters + h time-slot 0 --------------------
__global__ void zero_k(int* __restrict__ cnt, ushort_t* __restrict__ hglob) {
    int tid = blockIdx.x * blockDim.x + threadIdx.x;   // 1024 threads
    cnt[tid] = 0;                                      // 2*512 ints
    uint_t* h0 = (uint_t*)hglob;                       // dir0 slot0 (8192 uints)
    uint_t* h1 = (uint_t*)(hglob + (size_t)513 * HSLOT);
    for (int i = tid; i < HSLOT / 2; i += 1024) { h0[i] = 0; h1[i] = 0; }
}

// ---------------- K1: embeddings (B,T,E) f32 -> xbf (T,B,E) bf16 ------------
__global__ void conv_x(const float* __restrict__ emb, ushort_t* __restrict__ xbf) {
    int id = blockIdx.x * blockDim.x + threadIdx.x;      // over T*B*(E/4)
    int t  = id / (NB * (NE / 4));
    int rm = id - t * (NB * (NE / 4));
    int b  = rm / (NE / 4);
    int e4 = rm - b * (NE / 4);
    const float4 v = *(const float4*)(emb + ((size_t)b * NT + t) * NE + e4 * 4);
    ushort_t o[4] = { f2b(v.x), f2b(v.y), f2b(v.z), f2b(v.w) };
    *(uint2*)(xbf + ((size_t)t * NB + b) * NE + e4 * 4) = *(const uint2*)o;
}

// ---------------- K1b: weights -> bf16 (Wcat, Whh), bias concat -------------
__global__ void conv_w(const float* __restrict__ Wihf, const float* __restrict__ Wihb,
                       const float* __restrict__ Whhf, const float* __restrict__ Whhb,
                       const float* __restrict__ bf,   const float* __restrict__ bb,
                       ushort_t* __restrict__ wcat, ushort_t* __restrict__ whh,
                       float* __restrict__ bias) {
    int idx = blockIdx.x * blockDim.x + threadIdx.x;
    const int NW1 = NCC * NE;            // 1572864
    const int NW2 = 2 * NG * NH;         // 524288
    if (idx < NW1) {
        int row = idx / NE, col = idx - row * NE;
        float s = (row < NG) ? Wihf[(size_t)row * NE + col]
                             : Wihb[(size_t)(row - NG) * NE + col];
        wcat[idx] = f2b(s);
    } else if (idx < NW1 + NW2) {
        int j = idx - NW1;
        float s = (j < NG * NH) ? Whhf[j] : Whhb[j - NG * NH];
        whh[j] = f2b(s);
    } else if (idx < NW1 + NW2 + NCC) {
        int j = idx - NW1 - NW2;
        bias[j] = (j < NG) ? bf[j] : bb[j - NG];
    }
}

// ---------------- K2: xg = xbf(32768x768) @ wcat^T(2048x768) + bias ---------
__global__ __launch_bounds__(256) void gemm_xg(const ushort_t* __restrict__ A,
                                               const ushort_t* __restrict__ W,
                                               const float* __restrict__ bias,
                                               ushort_t* __restrict__ C) {
    __shared__ ushort_t As[128 * 72];
    __shared__ ushort_t Bs[128 * 72];
    const int tid = threadIdx.x;
    const int wave = tid >> 6, lane = tid & 63;
    const int q = lane >> 4, m16 = lane & 15;
    const int wm = wave & 1, wn = wave >> 1;
    const int m0 = blockIdx.y * 128, n0 = blockIdx.x * 128;

    floatx4 acc[4][4];
    #pragma unroll
    for (int i = 0; i < 4; ++i)
        #pragma unroll
        for (int j = 0; j < 4; ++j) acc[i][j] = (floatx4){0.f, 0.f, 0.f, 0.f};

    for (int kt = 0; kt < NE / 64; ++kt) {
        __syncthreads();
        #pragma unroll
        for (int it = 0; it < 4; ++it) {
            int chunk = tid + it * 256;         // 0..1023
            int row = chunk >> 3, kc = chunk & 7;
            *(uint4*)(&As[row * 72 + kc * 8]) =
                *(const uint4*)(A + (size_t)(m0 + row) * NE + kt * 64 + kc * 8);
            *(uint4*)(&Bs[row * 72 + kc * 8]) =
                *(const uint4*)(W + (size_t)(n0 + row) * NE + kt * 64 + kc * 8);
        }
        __syncthreads();
        #pragma unroll
        for (int ks = 0; ks < 2; ++ks) {
            short8 af[4], bfr[4];
            #pragma unroll
            for (int mt = 0; mt < 4; ++mt)
                af[mt] = *(const short8*)(&As[(wm * 64 + mt * 16 + m16) * 72 + ks * 32 + q * 8]);
            #pragma unroll
            for (int nt = 0; nt < 4; ++nt)
                bfr[nt] = *(const short8*)(&Bs[(wn * 64 + nt * 16 + m16) * 72 + ks * 32 + q * 8]);
            #pragma unroll
            for (int mt = 0; mt < 4; ++mt)
                #pragma unroll
                for (int nt = 0; nt < 4; ++nt)
                    acc[mt][nt] = __builtin_amdgcn_mfma_f32_16x16x32_bf16(
                        af[mt], bfr[nt], acc[mt][nt], 0, 0, 0);
        }
    }
    float bcol[4];
    #pragma unroll
    for (int nt = 0; nt < 4; ++nt) bcol[nt] = bias[n0 + wn * 64 + nt * 16 + m16];
    #pragma unroll
    for (int mt = 0; mt < 4; ++mt)
        #pragma unroll
        for (int nt = 0; nt < 4; ++nt) {
            int gn = n0 + wn * 64 + nt * 16 + m16;
            #pragma unroll
            for (int r = 0; r < 4; ++r) {
                int gm = m0 + wm * 64 + mt * 16 + q * 4 + r;
                C[(size_t)gm * NCC + gn] = f2b(acc[mt][nt][r] + bcol[nt]);
            }
        }
}

// ---------------- K3: recurrence, 16 WGs = 2 dirs x 8 gate-slices -----------
// WG (d,g): owns hidden units [g*32, g*32+32) => 128 gate rows, 64KB LDS.
// 512 threads = 8 waves = 4 batch-groups x 2 hu-groups.
__global__ __launch_bounds__(512, 1) void lstm_k(const ushort_t* __restrict__ xg,
                                                 const ushort_t* __restrict__ whh,
                                                 ushort_t* __restrict__ hglob,
                                                 int* __restrict__ cnt) {
    const int d = blockIdx.x >> 3;
    const int g = blockIdx.x & 7;
    const int tid = threadIdx.x;
    const int w = tid >> 6, lane = tid & 63;
    const int q = lane >> 4, m16 = lane & 15;
    const int bg = w & 3, hg = w >> 2;

    __shared__ ushort_t wlds[128 * 256];   // 64 KB, XOR-swizzled 8-elem chunks

    // Stage weight slice: LDS row = gate*32 + lhu; chunk c8 stored at c8^(row&7)
    for (int idx = tid; idx < 128 * 32; idx += 512) {
        int row = idx >> 5, c8 = idx & 31;
        int gate = row >> 5, lhu = row & 31;
        const ushort_t* src = whh + ((size_t)d * NG + gate * NH + g * HSL + lhu) * NH + c8 * 8;
        *(uint4*)(&wlds[row * 256 + ((c8 ^ (row & 7)) * 8)]) = *(const uint4*)src;
    }

    const int hu = g * HSL + hg * 16 + m16;     // global hidden unit
    float c[4] = {0.f, 0.f, 0.f, 0.f};
    ushort_t* hdir = hglob + (size_t)d * 513 * HSLOT;
    int* mycnt = cnt + d * NT;
    __syncthreads();

    for (int s = 0; s < NT; ++s) {
        const int t = d ? (NT - 1 - s) : s;

        // Prefetch xg (independent of h) before the spin.
        ushort_t xraw[4][4];
        #pragma unroll
        for (int nt = 0; nt < 4; ++nt)
            #pragma unroll
            for (int r = 0; r < 4; ++r)
                xraw[nt][r] = xg[(size_t)(t * NB + bg * 16 + q * 4 + r) * NCC
                                 + d * NG + nt * NH + hu];

        if (s > 0) {
            while (__hip_atomic_load(&mycnt[s - 1], __ATOMIC_RELAXED,
                                     __HIP_MEMORY_SCOPE_AGENT) < GPD)
                __builtin_amdgcn_s_sleep(1);
            __builtin_amdgcn_fence(__ATOMIC_ACQUIRE, "agent");
        }

        // A fragments: h_prev (64 x 256) from slot s
        const ushort_t* hprev = hdir + (size_t)s * HSLOT;
        short8 af[8];
        #pragma unroll
        for (int ks = 0; ks < 8; ++ks)
            af[ks] = *(const short8*)(hprev + (bg * 16 + m16) * NH + ks * 32 + q * 8);

        float gv[4][4];
        #pragma unroll
        for (int nt = 0; nt < 4; ++nt) {
            floatx4 acc = (floatx4){0.f, 0.f, 0.f, 0.f};
            const int row = nt * HSL + hg * 16 + m16;
            const int rx = row & 7;
            #pragma unroll
            for (int ks = 0; ks < 8; ++ks) {
                short8 bfr = *(const short8*)(&wlds[row * 256 + (((ks * 4 + q) ^ rx) * 8)]);
                acc = __builtin_amdgcn_mfma_f32_16x16x32_bf16(af[ks], bfr, acc, 0, 0, 0);
            }
            #pragma unroll
            for (int r = 0; r < 4; ++r) gv[nt][r] = acc[r] + b2f(xraw[nt][r]);
        }

        ushort_t* hout = hdir + (size_t)(s + 1) * HSLOT;
        #pragma unroll
        for (int r = 0; r < 4; ++r) {
            float ig = sigf(gv[0][r]);
            float fg = sigf(gv[1][r]);
            float gg = tanhfast(gv[2][r]);
            float og = sigf(gv[3][r]);
            c[r] = fg * c[r] + ig * gg;
            float h = og * tanhfast(c[r]);
            hout[(bg * 16 + q * 4 + r) * NH + hu] = f2b(h);
        }
        __syncthreads();                       // drains vmem (stores at L2)
        if (tid == 0) {
            __builtin_amdgcn_fence(__ATOMIC_RELEASE, "agent");   // wbl2: flush slice
            __hip_atomic_fetch_add(&mycnt[s], 1, __ATOMIC_RELAXED,
                                   __HIP_MEMORY_SCOPE_AGENT);
        }
    }
}

// ---------------- K4: em[t,b,l] = feats . W_lin[l] + b_lin ------------------
// fwd h(t) = hglob slot t+1 (dir0); bwd h(t) = hglob slot 512-t (dir1)
__global__ void em_k(const ushort_t* __restrict__ hglob, const float* __restrict__ Wlin,
                     const float* __restrict__ blin, float* __restrict__ em) {
    const int t = blockIdx.x;
    const int tid = threadIdx.x;          // 576 threads
    __shared__ float Ws[NL * 520];
    for (int idx = tid; idx < NL * 2 * NH; idx += 576) {
        int l = idx >> 9, k = idx & 511;
        Ws[l * 520 + k] = Wlin[l * 2 * NH + k];
    }
    __syncthreads();
    const int b = tid / NL, l = tid - b * NL;
    const ushort_t* hf = hglob + (size_t)(t + 1) * HSLOT + (size_t)b * NH;
    const ushort_t* hb = hglob + ((size_t)513 + (512 - t)) * HSLOT + (size_t)b * NH;
    float acc = blin[l];
    #pragma unroll 4
    for (int kc = 0; kc < NH / 8; ++kc) {
        uint4 u = *(const uint4*)(hf + kc * 8);
        const uint_t* uu = (const uint_t*)&u;
        #pragma unroll
        for (int j = 0; j < 4; ++j) {
            acc += b2f((ushort_t)(uu[j] & 0xFFFF)) * Ws[l * 520 + kc * 8 + 2 * j];
            acc += b2f((ushort_t)(uu[j] >> 16))    * Ws[l * 520 + kc * 8 + 2 * j + 1];
        }
    }
    #pragma unroll 4
    for (int kc = 0; kc < NH / 8; ++kc) {
        uint4 u = *(const uint4*)(hb + kc * 8);
        const uint_t* uu = (const uint_t*)&u;
        #pragma unroll
        for (int j = 0; j < 4; ++j) {
            acc += b2f((ushort_t)(uu[j] & 0xFFFF)) * Ws[l * 520 + NH + kc * 8 + 2 * j];
            acc += b2f((ushort_t)(uu[j] >> 16))    * Ws[l * 520 + NH + kc * 8 + 2 * j + 1];
        }
    }
    em[((size_t)t * NB + b) * NL + l] = acc;
}

// ---------------- K5: CRF numerator per batch -------------------------------
__global__ void num_k(const float* __restrict__ em, const int* __restrict__ mask,
                      const int* __restrict__ labels, const float* __restrict__ start,
                      const float* __restrict__ endt, const float* __restrict__ trans,
                      float* __restrict__ numbuf) {
    const int b = threadIdx.x;     // 64 threads, 1 block
    int len = 0;
    #pragma unroll 8
    for (int t = 0; t < NT; ++t) len += (mask[b * NT + t] != 0);
    int tag0 = labels[b * NT];
    float num = start[tag0] + em[(size_t)b * NL + tag0];
    #pragma unroll 4
    for (int t = 1; t < NT; ++t) {
        if (t < len) {
            int tp = labels[b * NT + t - 1];
            int tg = labels[b * NT + t];
            num += trans[tp * NL + tg] + em[((size_t)t * NB + b) * NL + tg];
        }
    }
    num += endt[labels[b * NT + len - 1]];
    numbuf[b] = num;
}

// ---------------- K6: CRF forward (logZ), diff = logZ - num -----------------
__global__ void crf_k(const float* __restrict__ em, const int* __restrict__ mask,
                      const float* __restrict__ start, const float* __restrict__ endt,
                      const float* __restrict__ trans, const float* __restrict__ numbuf,
                      float* __restrict__ diff) {
    const int b = blockIdx.x;
    const int lane = threadIdx.x;       // 64 threads = 1 wave
    int cnt = 0;
    for (int t = lane; t < NT; t += 64) cnt += (mask[b * NT + t] != 0);
    #pragma unroll
    for (int off = 32; off > 0; off >>= 1) cnt += __shfl_down(cnt, off);
    const int len = __shfl(cnt, 0);

    float tcol[NL];
    #pragma unroll
    for (int i = 0; i < NL; ++i) tcol[i] = (lane < NL) ? trans[i * NL + lane] : 0.f;
    float endv = (lane < NL) ? endt[lane] : 0.f;
    float score = (lane < NL) ? start[lane] + em[(size_t)b * NL + lane] : -1e30f;

    for (int t = 1; t < len; ++t) {
        float emv = (lane < NL) ? em[((size_t)t * NB + b) * NL + lane] : 0.f;
        float sv[NL];
        #pragma unroll
        for (int i = 0; i < NL; ++i) sv[i] = __shfl(score, i) + tcol[i];
        float m = sv[0];
        #pragma unroll
        for (int i = 1; i < NL; ++i) m = fmaxf(m, sv[i]);
        float sum = 0.f;
        #pragma unroll
        for (int i = 0; i < NL; ++i) sum += __expf(sv[i] - m);
        float nxt = m + __logf(sum) + emv;
        if (lane < NL) score = nxt;
    }
    float v = (lane < NL) ? score + endv : -1e30f;
    float m = -1e30f;
    float sv[NL];
    #pragma unroll
    for (int i = 0; i < NL; ++i) { sv[i] = __shfl(v, i); m = fmaxf(m, sv[i]); }
    float sum = 0.f;
    #pragma unroll
    for (int i = 0; i < NL; ++i) sum += __expf(sv[i] - m);
    float logZ = m + __logf(sum);
    if (lane == 0) diff[b] = logZ - numbuf[b];
}

// ---------------- K7: mean over batch -> d_out ------------------------------
__global__ void final_k(const float* __restrict__ diff, float* __restrict__ out) {
    float v = diff[threadIdx.x];
    #pragma unroll
    for (int off = 32; off > 0; off >>= 1) v += __shfl_down(v, off);
    if (threadIdx.x == 0) out[0] = v * (1.0f / NB);
}

extern "C" void kernel_launch(void* const* d_in, const int* in_sizes, int n_in,
                              void* d_out, int out_size, void* d_ws, size_t ws_size,
                              hipStream_t stream) {
    const float* emb   = (const float*)d_in[0];
    const float* Wihf  = (const float*)d_in[1];
    const float* Whhf  = (const float*)d_in[2];
    const float* bf    = (const float*)d_in[3];
    const float* Wihb  = (const float*)d_in[4];
    const float* Whhb  = (const float*)d_in[5];
    const float* bb    = (const float*)d_in[6];
    const float* Wlin  = (const float*)d_in[7];
    const float* blin  = (const float*)d_in[8];
    const float* start = (const float*)d_in[9];
    const float* endt  = (const float*)d_in[10];
    const float* trans = (const float*)d_in[11];
    const int*   mask  = (const int*)d_in[12];
    const int*   labels= (const int*)d_in[13];

    char* ws = (char*)d_ws;
    ushort_t* xbf   = (ushort_t*)(ws + 0);                     // 50,331,648
    ushort_t* wcat  = (ushort_t*)(ws + 50331648);              //  3,145,728
    ushort_t* whhbf = (ushort_t*)(ws + 53477376);              //  1,048,576
    float*    bias  = (float*)   (ws + 54525952);              //      8,192
    ushort_t* xg    = (ushort_t*)(ws + 54534144);              // 134,217,728
    ushort_t* hglob = (ushort_t*)(ws + 188751872);             // 33,619,968
    float*    em    = (float*)   (ws + 222371840);             //  1,179,648
    float*    numb  = (float*)   (ws + 223551488);             //        256
    float*    diff  = (float*)   (ws + 223551744);             //        256
    int*      cnt   = (int*)     (ws + 223552000);             //      4,096

    zero_k<<<4, 256, 0, stream>>>(cnt, hglob);
    conv_x<<<NT * NB * (NE / 4) / 256, 256, 0, stream>>>(emb, xbf);
    conv_w<<<(NCC * NE + 2 * NG * NH + NCC) / 256, 256, 0, stream>>>(
        Wihf, Wihb, Whhf, Whhb, bf, bb, wcat, whhbf, bias);
    gemm_xg<<<dim3(NCC / 128, NT * NB / 128), 256, 0, stream>>>(xbf, wcat, bias, xg);
    lstm_k<<<16, 512, 0, stream>>>(xg, whhbf, hglob, cnt);
    em_k<<<NT, 576, 0, stream>>>(hglob, Wlin, blin, em);
    num_k<<<1, 64, 0, stream>>>(em, mask, labels, start, endt, trans, numb);
    crf_k<<<NB, 64, 0, stream>>>(em, mask, start, endt, trans, numb, diff);
    final_k<<<1, 64, 0, stream>>>(diff, (float*)d_out);
}